// Round 14
// baseline (321.924 us; speedup 1.0000x reference)
//
#include <hip/hip_runtime.h>

#define NN 100000
#define NE 1600000
#define NPB 256                    // nodes per bucket
#define NB 391                     // ceil(NN/NPB)
#define CAP 4864                   // bucket capacity (mean 4092, sd 64)
#define NBLK_A 512
#define CHUNK_A (NE / NBLK_A)      // 3125
#define CVT_N (NN * 16)            // 1.6M cvt threads (8 floats each)
#define PREP_BLKS ((CVT_N + 10240) / 256)   // 6290 exact

typedef __attribute__((ext_vector_type(8))) short bf16x8;
typedef __attribute__((ext_vector_type(4))) float f32x4;
typedef __attribute__((ext_vector_type(4))) unsigned int uint32x4;

// ---------------- bf16 helpers (stored as ushort/uint, math in fp32) ----------------

__device__ __forceinline__ unsigned short f2bf(float f) {
    unsigned int u = __float_as_uint(f);
    unsigned int r = u + 0x7fffu + ((u >> 16) & 1u);  // RNE
    return (unsigned short)(r >> 16);
}
__device__ __forceinline__ float bflo(unsigned int u) { return __uint_as_float(u << 16); }
__device__ __forceinline__ float bfhi(unsigned int u) { return __uint_as_float(u & 0xffff0000u); }
__device__ __forceinline__ unsigned int packbf(float lo, float hi) {
    return ((unsigned int)f2bf(hi) << 16) | (unsigned int)f2bf(lo);
}
__device__ __forceinline__ bf16x8 as_bf8(uint4 u) {
    union { uint4 u; bf16x8 h; } c;
    c.u = u;
    return c.h;
}

// ---------------- weight -> MFMA B-fragment layout ----------------
// frag[(kt*(H/16)+nt)*64 + lane], elem i = W[kt*32 + (lane>>4)*8 + i][nt*16 + (lane&15)]

__device__ __forceinline__ void wfrag_one(const float* __restrict__ W, int H, int idx,
                                          uint4* __restrict__ out) {
    int lane = idx & 63;
    int tile = idx >> 6;
    int ntiles = H >> 4;
    int nt = tile % ntiles;
    int kt = tile / ntiles;
    int kbase = kt * 32 + (lane >> 4) * 8;
    int col = nt * 16 + (lane & 15);
    uint4 r;
    r.x = packbf(W[(size_t)(kbase + 0) * H + col], W[(size_t)(kbase + 1) * H + col]);
    r.y = packbf(W[(size_t)(kbase + 2) * H + col], W[(size_t)(kbase + 3) * H + col]);
    r.z = packbf(W[(size_t)(kbase + 4) * H + col], W[(size_t)(kbase + 5) * H + col]);
    r.w = packbf(W[(size_t)(kbase + 6) * H + col], W[(size_t)(kbase + 7) * H + col]);
    out[idx] = r;
}

// ---------------- fused: bucket scatter (blocks 0..511) + prep (remaining blocks) ----------------

__global__ __launch_bounds__(256) void scatter_prep_kernel(
    const int* __restrict__ src, const int* __restrict__ dst,
    int* __restrict__ gcur, unsigned* __restrict__ buckets,
    const float* __restrict__ x, unsigned int* __restrict__ x_bf,
    const float* __restrict__ W1l, const float* __restrict__ W1r,
    const float* __restrict__ W2l, const float* __restrict__ W2r,
    const float* __restrict__ W3l, const float* __restrict__ W3r,
    uint4* __restrict__ wf1, uint4* __restrict__ wf2,
    uint4* __restrict__ wf3l, uint4* __restrict__ wf3r) {
    __shared__ int hist[NB];
    __shared__ int base[NB];
    int t = threadIdx.x;

    if (blockIdx.x < NBLK_A) {
        for (int b = t; b < NB; b += 256) hist[b] = 0;
        __syncthreads();
        int e0 = blockIdx.x * CHUNK_A;
        for (int e = e0 + t; e < e0 + CHUNK_A; e += 256)
            atomicAdd(&hist[dst[e] >> 8], 1);
        __syncthreads();
        for (int b = t; b < NB; b += 256) {
            base[b] = atomicAdd(&gcur[b], hist[b]);
            hist[b] = 0;
        }
        __syncthreads();
        for (int e = e0 + t; e < e0 + CHUNK_A; e += 256) {
            int d = dst[e];
            int bkt = d >> 8;
            int slot = base[bkt] + atomicAdd(&hist[bkt], 1);
            if (slot < CAP)
                buckets[(size_t)bkt * CAP + slot] =
                    ((unsigned)(d & 255) << 24) | (unsigned)src[e];
        }
    } else {
        int idx = (blockIdx.x - NBLK_A) * 256 + t;
        if (idx < CVT_N) {
            const float4* p = (const float4*)x + (size_t)idx * 2;
            float4 a = p[0], b = p[1];
            uint4 r;
            r.x = packbf(a.x, a.y);
            r.y = packbf(a.z, a.w);
            r.z = packbf(b.x, b.y);
            r.w = packbf(b.z, b.w);
            ((uint4*)x_bf)[idx] = r;
        } else {
            int k = idx - CVT_N;
            if (k < 2048)       wfrag_one(W1l, 128, k, wf1);
            else if (k < 4096)  wfrag_one(W1r, 128, k - 2048, wf1 + 2048);
            else if (k < 6144)  wfrag_one(W2l, 128, k - 4096, wf2);
            else if (k < 8192)  wfrag_one(W2r, 128, k - 6144, wf2 + 2048);
            else if (k < 9216)  wfrag_one(W3l, 64, k - 8192, wf3l);
            else if (k < 10240) wfrag_one(W3r, 64, k - 9216, wf3r);
        }
    }
}

// ---------------- CSR finalize with inline bucket-prefix scan (one block per bucket) ----------------

__global__ __launch_bounds__(256) void csr_finalize_kernel(
    const unsigned* __restrict__ buckets, const int* __restrict__ gcur,
    int* __restrict__ row_ptr, int* __restrict__ adj) {
    __shared__ int hist[NPB];
    __shared__ int scn[NPB];
    int b = blockIdx.x;
    int t = threadIdx.x;

    // base = sum gcur[0..b)
    int part = 0;
    for (int j = t; j < b; j += 256) part += gcur[j];
    scn[t] = part;
    __syncthreads();
    for (int off = 128; off > 0; off >>= 1) {
        if (t < off) scn[t] += scn[t + off];
        __syncthreads();
    }
    int base = scn[0];

    int nraw = gcur[b];
    int n = (nraw > CAP) ? CAP : nraw;
    if (b == NB - 1 && t == 0) row_ptr[NN] = base + nraw;
    const unsigned* bk = buckets + (size_t)b * CAP;

    hist[t] = 0;
    __syncthreads();
    for (int i = t; i < n; i += 256) atomicAdd(&hist[bk[i] >> 24], 1);
    __syncthreads();

    int v = hist[t];
    scn[t] = v;
    __syncthreads();
    for (int off = 1; off < 256; off <<= 1) {
        int add = (t >= off) ? scn[t - off] : 0;
        __syncthreads();
        scn[t] += add;
        __syncthreads();
    }
    int excl = scn[t] - v;
    int node = b * NPB + t;
    if (node < NN) row_ptr[node] = base + excl;

    hist[t] = excl;  // reuse as cursor
    __syncthreads();
    for (int i = t; i < n; i += 256) {
        unsigned pr = bk[i];
        int pos = atomicAdd(&hist[pr >> 24], 1);
        adj[base + pos] = (int)(pr & 0xFFFFFFu);
    }
}

// ---------------- pull_mean 128-wide: 1 node per 16-lane group, pipelined edges ----------------
// 4 nodes/wave, 16 nodes/block (grid 6250). Lane i owns chunk i: no shuffles, no masks.
// Software-pipelined: batch k+1's adj+row loads issued before batch k's accumulate
// (8 gathers outstanding at issue). NT hints on adj (streamed once) and agg (write-once).

__global__ __launch_bounds__(256) void pull128_kernel(
    const uint4* __restrict__ xb4, const int* __restrict__ row_ptr,
    const int* __restrict__ adj, unsigned int* __restrict__ aggb) {
    const int l = threadIdx.x & 63;
    const int g = l >> 4;
    const int i = l & 15;
    const int node = blockIdx.x * 16 + (threadIdx.x >> 6) * 4 + g;
    const int beg = row_ptr[node], end = row_ptr[node + 1];

    float acc[8];
#pragma unroll
    for (int j = 0; j < 8; ++j) acc[j] = 0.f;

#define ACC4_128(U)                                 \
    do {                                            \
        acc[0] += bflo((U).x); acc[1] += bfhi((U).x); \
        acc[2] += bflo((U).y); acc[3] += bfhi((U).y); \
        acc[4] += bflo((U).z); acc[5] += bfhi((U).z); \
        acc[6] += bflo((U).w); acc[7] += bfhi((U).w); \
    } while (0)

    int p = beg;
    int nfull = (end - beg) >> 2;
    if (nfull > 0) {
        int s0 = __builtin_nontemporal_load(adj + p + 0);
        int s1 = __builtin_nontemporal_load(adj + p + 1);
        int s2 = __builtin_nontemporal_load(adj + p + 2);
        int s3 = __builtin_nontemporal_load(adj + p + 3);
        uint4 a0 = xb4[(size_t)s0 * 16 + i];
        uint4 a1 = xb4[(size_t)s1 * 16 + i];
        uint4 a2 = xb4[(size_t)s2 * 16 + i];
        uint4 a3 = xb4[(size_t)s3 * 16 + i];
        p += 4;
        for (int it = 1; it < nfull; ++it, p += 4) {
            int t0 = __builtin_nontemporal_load(adj + p + 0);
            int t1 = __builtin_nontemporal_load(adj + p + 1);
            int t2 = __builtin_nontemporal_load(adj + p + 2);
            int t3 = __builtin_nontemporal_load(adj + p + 3);
            uint4 b0 = xb4[(size_t)t0 * 16 + i];
            uint4 b1 = xb4[(size_t)t1 * 16 + i];
            uint4 b2 = xb4[(size_t)t2 * 16 + i];
            uint4 b3 = xb4[(size_t)t3 * 16 + i];
            ACC4_128(a0);
            ACC4_128(a1);
            ACC4_128(a2);
            ACC4_128(a3);
            a0 = b0; a1 = b1; a2 = b2; a3 = b3;
        }
        ACC4_128(a0);
        ACC4_128(a1);
        ACC4_128(a2);
        ACC4_128(a3);
    }
    for (; p < end; ++p) {
        int s = __builtin_nontemporal_load(adj + p);
        uint4 u = xb4[(size_t)s * 16 + i];
        ACC4_128(u);
    }
#undef ACC4_128

    float inv = 1.0f / (float)(end > beg ? (end - beg) : 1);
    uint32x4 r;
    r.x = packbf(acc[0] * inv, acc[1] * inv);
    r.y = packbf(acc[2] * inv, acc[3] * inv);
    r.z = packbf(acc[4] * inv, acc[5] * inv);
    r.w = packbf(acc[6] * inv, acc[7] * inv);
    __builtin_nontemporal_store(r, (uint32x4*)(aggb + (size_t)node * 64 + i * 4));
}

// ---------------- pull_mean 64-wide (z): same structure, uint2 chunks, fp32 out ----------------

__global__ __launch_bounds__(256) void pull64_kernel(
    const uint2* __restrict__ zb2, const int* __restrict__ row_ptr,
    const int* __restrict__ adj, float* __restrict__ aggout) {
    const int l = threadIdx.x & 63;
    const int g = l >> 4;
    const int i = l & 15;
    const int node = blockIdx.x * 16 + (threadIdx.x >> 6) * 4 + g;
    const int beg = row_ptr[node], end = row_ptr[node + 1];

    float acc[4];
#pragma unroll
    for (int j = 0; j < 4; ++j) acc[j] = 0.f;

#define ACC4_64(U)                                  \
    do {                                            \
        acc[0] += bflo((U).x); acc[1] += bfhi((U).x); \
        acc[2] += bflo((U).y); acc[3] += bfhi((U).y); \
    } while (0)

    int p = beg;
    int nfull = (end - beg) >> 2;
    if (nfull > 0) {
        int s0 = __builtin_nontemporal_load(adj + p + 0);
        int s1 = __builtin_nontemporal_load(adj + p + 1);
        int s2 = __builtin_nontemporal_load(adj + p + 2);
        int s3 = __builtin_nontemporal_load(adj + p + 3);
        uint2 a0 = zb2[(size_t)s0 * 16 + i];
        uint2 a1 = zb2[(size_t)s1 * 16 + i];
        uint2 a2 = zb2[(size_t)s2 * 16 + i];
        uint2 a3 = zb2[(size_t)s3 * 16 + i];
        p += 4;
        for (int it = 1; it < nfull; ++it, p += 4) {
            int t0 = __builtin_nontemporal_load(adj + p + 0);
            int t1 = __builtin_nontemporal_load(adj + p + 1);
            int t2 = __builtin_nontemporal_load(adj + p + 2);
            int t3 = __builtin_nontemporal_load(adj + p + 3);
            uint2 b0 = zb2[(size_t)t0 * 16 + i];
            uint2 b1 = zb2[(size_t)t1 * 16 + i];
            uint2 b2 = zb2[(size_t)t2 * 16 + i];
            uint2 b3 = zb2[(size_t)t3 * 16 + i];
            ACC4_64(a0);
            ACC4_64(a1);
            ACC4_64(a2);
            ACC4_64(a3);
            a0 = b0; a1 = b1; a2 = b2; a3 = b3;
        }
        ACC4_64(a0);
        ACC4_64(a1);
        ACC4_64(a2);
        ACC4_64(a3);
    }
    for (; p < end; ++p) {
        int s = __builtin_nontemporal_load(adj + p);
        uint2 u = zb2[(size_t)s * 16 + i];
        ACC4_64(u);
    }
#undef ACC4_64

    float inv = 1.0f / (float)(end > beg ? (end - beg) : 1);
    f32x4 w;
    w.x = acc[0] * inv;
    w.y = acc[1] * inv;
    w.z = acc[2] * inv;
    w.w = acc[3] * inv;
    __builtin_nontemporal_store(w, (f32x4*)(aggout + (size_t)node * 64 + i * 4));
}

// ---------------- MFMA SAGE layer (H=128): out = relu(agg@Wl + xin@Wr + b) ----------------
// FUSE_Z: additionally z = h @ Wz via LDS C->A transpose (bit-identical to a separate
// matmul over the bf16 h). __syncthreads() guarantees LDS write->read ordering.

template <bool FUSE_Z>
__global__ __launch_bounds__(256) void sage_mfma_kernel(
    const uint4* __restrict__ aggA, const uint4* __restrict__ xinA,
    const uint4* __restrict__ wfrag, const float* __restrict__ bias,
    unsigned short* __restrict__ outb,
    const uint4* __restrict__ wfz, unsigned short* __restrict__ zout) {
    extern __shared__ unsigned short hts[];  // FUSE_Z: 4 waves x [16][136]

    const int w = threadIdx.x >> 6;
    const int l = threadIdx.x & 63;
    const int r0 = blockIdx.x * 64 + w * 16;
    int arow = r0 + (l & 15);
    if (arow > NN - 1) arow = NN - 1;
    const int koff = l >> 4;

    f32x4 acc[8];
#pragma unroll
    for (int nt = 0; nt < 8; ++nt) {
        f32x4 z = {0.f, 0.f, 0.f, 0.f};
        acc[nt] = z;
    }

#pragma unroll
    for (int kt = 0; kt < 8; ++kt) {
        const uint4* Ab = (kt < 4) ? aggA : xinA;
        const int ktl = kt & 3;
        bf16x8 av = as_bf8(Ab[(size_t)arow * 16 + ktl * 4 + koff]);
#pragma unroll
        for (int nt = 0; nt < 8; ++nt) {
            bf16x8 bv = as_bf8(wfrag[(kt * 8 + nt) * 64 + l]);
            acc[nt] = __builtin_amdgcn_mfma_f32_16x16x32_bf16(av, bv, acc[nt], 0, 0, 0);
        }
    }

    const int crow0 = r0 + ((l >> 4) << 2);
    const int ccol = l & 15;
#pragma unroll
    for (int nt = 0; nt < 8; ++nt) {
        float bb = bias[nt * 16 + ccol];
#pragma unroll
        for (int q = 0; q < 4; ++q) {
            int r = crow0 + q;
            unsigned short hb = f2bf(fmaxf(acc[nt][q] + bb, 0.f));
            if (r < NN) outb[(size_t)r * 128 + nt * 16 + ccol] = hb;
            if (FUSE_Z) {
                hts[((size_t)w * 16 + ((l >> 4) << 2) + q) * 136 + nt * 16 + ccol] = hb;
            }
        }
    }

    if (FUSE_Z) {
        __syncthreads();
        f32x4 accz[4];
#pragma unroll
        for (int nt = 0; nt < 4; ++nt) {
            f32x4 z = {0.f, 0.f, 0.f, 0.f};
            accz[nt] = z;
        }
#pragma unroll
        for (int kt = 0; kt < 4; ++kt) {
            const uint4 hv =
                *(const uint4*)&hts[((size_t)w * 16 + (l & 15)) * 136 + kt * 32 + (l >> 4) * 8];
            bf16x8 av = as_bf8(hv);
#pragma unroll
            for (int nt = 0; nt < 4; ++nt) {
                bf16x8 bv = as_bf8(wfz[(kt * 4 + nt) * 64 + l]);
                accz[nt] = __builtin_amdgcn_mfma_f32_16x16x32_bf16(av, bv, accz[nt], 0, 0, 0);
            }
        }
#pragma unroll
        for (int nt = 0; nt < 4; ++nt) {
#pragma unroll
            for (int q = 0; q < 4; ++q) {
                int r = crow0 + q;
                if (r < NN) zout[(size_t)r * 64 + nt * 16 + ccol] = f2bf(accz[nt][q]);
            }
        }
    }
}

// ---------------- final MFMA matmul: out = h2 @ W3r + agg3 + b3 (fp32) ----------------

__global__ __launch_bounds__(256) void mm64_final_kernel(
    const uint4* __restrict__ A, const uint4* __restrict__ wfrag,
    const float* __restrict__ addin, const float* __restrict__ bias,
    float* __restrict__ out) {
    const int w = threadIdx.x >> 6;
    const int l = threadIdx.x & 63;
    const int r0 = blockIdx.x * 64 + w * 16;
    int arow = r0 + (l & 15);
    if (arow > NN - 1) arow = NN - 1;
    const int koff = l >> 4;

    f32x4 acc[4];
#pragma unroll
    for (int nt = 0; nt < 4; ++nt) {
        f32x4 z = {0.f, 0.f, 0.f, 0.f};
        acc[nt] = z;
    }

#pragma unroll
    for (int kt = 0; kt < 4; ++kt) {
        bf16x8 av = as_bf8(A[(size_t)arow * 16 + kt * 4 + koff]);
#pragma unroll
        for (int nt = 0; nt < 4; ++nt) {
            bf16x8 bv = as_bf8(wfrag[(kt * 4 + nt) * 64 + l]);
            acc[nt] = __builtin_amdgcn_mfma_f32_16x16x32_bf16(av, bv, acc[nt], 0, 0, 0);
        }
    }

    const int crow0 = r0 + ((l >> 4) << 2);
    const int ccol = l & 15;
#pragma unroll
    for (int nt = 0; nt < 4; ++nt) {
        int col = nt * 16 + ccol;
#pragma unroll
        for (int q = 0; q < 4; ++q) {
            int r = crow0 + q;
            if (r < NN) {
                out[(size_t)r * 64 + col] =
                    acc[nt][q] + addin[(size_t)r * 64 + col] + bias[col];
            }
        }
    }
}

// ---------------- launcher ----------------

extern "C" void kernel_launch(void* const* d_in, const int* in_sizes, int n_in,
                              void* d_out, int out_size, void* d_ws, size_t ws_size,
                              hipStream_t stream) {
    (void)in_sizes; (void)n_in; (void)out_size; (void)ws_size;

    const float* x   = (const float*)d_in[0];
    const int* eidx  = (const int*)d_in[1];
    const int* src   = eidx;
    const int* dst   = eidx + NE;
    const float* W1l = (const float*)d_in[2];
    const float* W1r = (const float*)d_in[3];
    const float* b1  = (const float*)d_in[4];
    const float* W2l = (const float*)d_in[5];
    const float* W2r = (const float*)d_in[6];
    const float* b2  = (const float*)d_in[7];
    const float* W3l = (const float*)d_in[8];
    const float* W3r = (const float*)d_in[9];
    const float* b3  = (const float*)d_in[10];
    float* out = (float*)d_out;

    size_t off = 0;
    auto carve = [&](size_t bytes) -> void* {
        void* p = (char*)d_ws + off;
        off += (bytes + 255) & ~(size_t)255;
        return p;
    };
    int* gcur    = (int*)carve((size_t)NB * 4);
    int* row_ptr = (int*)carve((size_t)(NN + 1) * 4);
    int* adj     = (int*)carve((size_t)NE * 4);
    unsigned* buckets = (unsigned*)carve((size_t)NB * CAP * 4);         // 7.6 MB
    unsigned int* x_bf  = (unsigned int*)carve((size_t)NN * 64 * 4);    // [NN][128] bf16
    unsigned int* agg   = (unsigned int*)carve((size_t)NN * 64 * 4);    // [NN][128] bf16
    unsigned int* h1_bf = (unsigned int*)carve((size_t)NN * 64 * 4);
    unsigned int* h2_bf = (unsigned int*)carve((size_t)NN * 64 * 4);
    unsigned int* z_bf  = (unsigned int*)carve((size_t)NN * 32 * 4);    // [NN][64] bf16
    float* agg3         = (float*)carve((size_t)NN * 64 * 4);           // [NN][64] fp32
    uint4* wf1  = (uint4*)carve((size_t)8 * 8 * 64 * 16);
    uint4* wf2  = (uint4*)carve((size_t)8 * 8 * 64 * 16);
    uint4* wf3l = (uint4*)carve((size_t)4 * 4 * 64 * 16);
    uint4* wf3r = (uint4*)carve((size_t)4 * 4 * 64 * 16);

    const int pgrid = NN / 16;                              // 6250 exact
    const int mgrid = (NN + 63) / 64;                       // 1563

    // --- fused CSR-scatter + prep (independent halves), then finalize (inline scan) ---
    (void)hipMemsetAsync(gcur, 0, (size_t)NB * 4, stream);
    scatter_prep_kernel<<<NBLK_A + PREP_BLKS, 256, 0, stream>>>(
        src, dst, gcur, buckets, x, x_bf, W1l, W1r, W2l, W2r, W3l, W3r,
        wf1, wf2, wf3l, wf3r);
    csr_finalize_kernel<<<NB, 256, 0, stream>>>(buckets, gcur, row_ptr, adj);

    // --- layer 1 ---
    pull128_kernel<<<pgrid, 256, 0, stream>>>((const uint4*)x_bf, row_ptr, adj, agg);
    sage_mfma_kernel<false><<<mgrid, 256, 0, stream>>>(
        (const uint4*)agg, (const uint4*)x_bf, wf1, b1, (unsigned short*)h1_bf,
        nullptr, nullptr);
    // --- layer 2 (+ fused z = h2 @ W3l) ---
    pull128_kernel<<<pgrid, 256, 0, stream>>>((const uint4*)h1_bf, row_ptr, adj, agg);
    sage_mfma_kernel<true><<<mgrid, 256, 4 * 16 * 136 * 2, stream>>>(
        (const uint4*)agg, (const uint4*)h1_bf, wf2, b2, (unsigned short*)h2_bf,
        wf3l, (unsigned short*)z_bf);
    // --- layer 3 ---
    pull64_kernel<<<pgrid, 256, 0, stream>>>((const uint2*)z_bf, row_ptr, adj, agg3);
    mm64_final_kernel<<<mgrid, 256, 0, stream>>>((const uint4*)h2_bf, wf3r, agg3, b3, out);
}

// Round 15
// 299.366 us; speedup vs baseline: 1.0754x; 1.0754x over previous
//
#include <hip/hip_runtime.h>

#define NN 100000
#define NE 1600000
#define NPB 256                    // nodes per bucket
#define NB 391                     // ceil(NN/NPB)
#define CAP 4864                   // bucket capacity (mean 4092, sd 64)
#define NBLK_A 512
#define CHUNK_A (NE / NBLK_A)      // 3125
#define CVT_N (NN * 16)            // 1.6M cvt threads (8 floats each)
#define PREP_BLKS ((CVT_N + 10240) / 256)   // 6290 exact

typedef __attribute__((ext_vector_type(8))) short bf16x8;
typedef __attribute__((ext_vector_type(4))) float f32x4;

// ---------------- bf16 helpers (stored as ushort/uint, math in fp32) ----------------

__device__ __forceinline__ unsigned short f2bf(float f) {
    unsigned int u = __float_as_uint(f);
    unsigned int r = u + 0x7fffu + ((u >> 16) & 1u);  // RNE
    return (unsigned short)(r >> 16);
}
__device__ __forceinline__ float bflo(unsigned int u) { return __uint_as_float(u << 16); }
__device__ __forceinline__ float bfhi(unsigned int u) { return __uint_as_float(u & 0xffff0000u); }
__device__ __forceinline__ unsigned int packbf(float lo, float hi) {
    return ((unsigned int)f2bf(hi) << 16) | (unsigned int)f2bf(lo);
}
__device__ __forceinline__ bf16x8 as_bf8(uint4 u) {
    union { uint4 u; bf16x8 h; } c;
    c.u = u;
    return c.h;
}

// ---------------- weight -> MFMA B-fragment layout ----------------
// frag[(kt*(H/16)+nt)*64 + lane], elem i = W[kt*32 + (lane>>4)*8 + i][nt*16 + (lane&15)]

__device__ __forceinline__ void wfrag_one(const float* __restrict__ W, int H, int idx,
                                          uint4* __restrict__ out) {
    int lane = idx & 63;
    int tile = idx >> 6;
    int ntiles = H >> 4;
    int nt = tile % ntiles;
    int kt = tile / ntiles;
    int kbase = kt * 32 + (lane >> 4) * 8;
    int col = nt * 16 + (lane & 15);
    uint4 r;
    r.x = packbf(W[(size_t)(kbase + 0) * H + col], W[(size_t)(kbase + 1) * H + col]);
    r.y = packbf(W[(size_t)(kbase + 2) * H + col], W[(size_t)(kbase + 3) * H + col]);
    r.z = packbf(W[(size_t)(kbase + 4) * H + col], W[(size_t)(kbase + 5) * H + col]);
    r.w = packbf(W[(size_t)(kbase + 6) * H + col], W[(size_t)(kbase + 7) * H + col]);
    out[idx] = r;
}

// ---------------- fused: bucket scatter (blocks 0..511) + prep (remaining blocks) ----------------

__global__ __launch_bounds__(256) void scatter_prep_kernel(
    const int* __restrict__ src, const int* __restrict__ dst,
    int* __restrict__ gcur, unsigned* __restrict__ buckets,
    const float* __restrict__ x, unsigned int* __restrict__ x_bf,
    const float* __restrict__ W1l, const float* __restrict__ W1r,
    const float* __restrict__ W2l, const float* __restrict__ W2r,
    const float* __restrict__ W3l, const float* __restrict__ W3r,
    uint4* __restrict__ wf1, uint4* __restrict__ wf2,
    uint4* __restrict__ wf3l, uint4* __restrict__ wf3r) {
    __shared__ int hist[NB];
    __shared__ int base[NB];
    int t = threadIdx.x;

    if (blockIdx.x < NBLK_A) {
        for (int b = t; b < NB; b += 256) hist[b] = 0;
        __syncthreads();
        int e0 = blockIdx.x * CHUNK_A;
        for (int e = e0 + t; e < e0 + CHUNK_A; e += 256)
            atomicAdd(&hist[dst[e] >> 8], 1);
        __syncthreads();
        for (int b = t; b < NB; b += 256) {
            base[b] = atomicAdd(&gcur[b], hist[b]);
            hist[b] = 0;
        }
        __syncthreads();
        for (int e = e0 + t; e < e0 + CHUNK_A; e += 256) {
            int d = dst[e];
            int bkt = d >> 8;
            int slot = base[bkt] + atomicAdd(&hist[bkt], 1);
            if (slot < CAP)
                buckets[(size_t)bkt * CAP + slot] =
                    ((unsigned)(d & 255) << 24) | (unsigned)src[e];
        }
    } else {
        int idx = (blockIdx.x - NBLK_A) * 256 + t;
        if (idx < CVT_N) {
            const float4* p = (const float4*)x + (size_t)idx * 2;
            float4 a = p[0], b = p[1];
            uint4 r;
            r.x = packbf(a.x, a.y);
            r.y = packbf(a.z, a.w);
            r.z = packbf(b.x, b.y);
            r.w = packbf(b.z, b.w);
            ((uint4*)x_bf)[idx] = r;
        } else {
            int k = idx - CVT_N;
            if (k < 2048)       wfrag_one(W1l, 128, k, wf1);
            else if (k < 4096)  wfrag_one(W1r, 128, k - 2048, wf1 + 2048);
            else if (k < 6144)  wfrag_one(W2l, 128, k - 4096, wf2);
            else if (k < 8192)  wfrag_one(W2r, 128, k - 6144, wf2 + 2048);
            else if (k < 9216)  wfrag_one(W3l, 64, k - 8192, wf3l);
            else if (k < 10240) wfrag_one(W3r, 64, k - 9216, wf3r);
        }
    }
}

// ---------------- CSR finalize with inline bucket-prefix scan (one block per bucket) ----------------

__global__ __launch_bounds__(256) void csr_finalize_kernel(
    const unsigned* __restrict__ buckets, const int* __restrict__ gcur,
    int* __restrict__ row_ptr, int* __restrict__ adj) {
    __shared__ int hist[NPB];
    __shared__ int scn[NPB];
    int b = blockIdx.x;
    int t = threadIdx.x;

    // base = sum gcur[0..b)
    int part = 0;
    for (int j = t; j < b; j += 256) part += gcur[j];
    scn[t] = part;
    __syncthreads();
    for (int off = 128; off > 0; off >>= 1) {
        if (t < off) scn[t] += scn[t + off];
        __syncthreads();
    }
    int base = scn[0];

    int nraw = gcur[b];
    int n = (nraw > CAP) ? CAP : nraw;
    if (b == NB - 1 && t == 0) row_ptr[NN] = base + nraw;
    const unsigned* bk = buckets + (size_t)b * CAP;

    hist[t] = 0;
    __syncthreads();
    for (int i = t; i < n; i += 256) atomicAdd(&hist[bk[i] >> 24], 1);
    __syncthreads();

    int v = hist[t];
    scn[t] = v;
    __syncthreads();
    for (int off = 1; off < 256; off <<= 1) {
        int add = (t >= off) ? scn[t - off] : 0;
        __syncthreads();
        scn[t] += add;
        __syncthreads();
    }
    int excl = scn[t] - v;
    int node = b * NPB + t;
    if (node < NN) row_ptr[node] = base + excl;

    hist[t] = excl;  // reuse as cursor
    __syncthreads();
    for (int i = t; i < n; i += 256) {
        unsigned pr = bk[i];
        int pos = atomicAdd(&hist[pr >> 24], 1);
        adj[base + pos] = (int)(pr & 0xFFFFFFu);
    }
}

// ---------------- pull_mean 128-wide: 1 node per 16-lane group, serial edges ----------------
// 4 nodes/wave, 16 nodes/block (grid 6250). Lane i owns chunk i forever: no shuffles,
// no masked gathers. Main loop 4 edges unrolled (4 rows in flight per group), exact tail.

__global__ __launch_bounds__(256) void pull128_kernel(
    const uint4* __restrict__ xb4, const int* __restrict__ row_ptr,
    const int* __restrict__ adj, uint4* __restrict__ aggb4) {
    const int l = threadIdx.x & 63;
    const int g = l >> 4;
    const int i = l & 15;
    const int node = blockIdx.x * 16 + (threadIdx.x >> 6) * 4 + g;
    const int beg = row_ptr[node], end = row_ptr[node + 1];

    float acc[8];
#pragma unroll
    for (int j = 0; j < 8; ++j) acc[j] = 0.f;

    int p = beg;
    for (; p + 4 <= end; p += 4) {
        int s0 = adj[p + 0], s1 = adj[p + 1], s2 = adj[p + 2], s3 = adj[p + 3];
        uint4 u0 = xb4[(size_t)s0 * 16 + i];
        uint4 u1 = xb4[(size_t)s1 * 16 + i];
        uint4 u2 = xb4[(size_t)s2 * 16 + i];
        uint4 u3 = xb4[(size_t)s3 * 16 + i];
        acc[0] += (bflo(u0.x) + bflo(u1.x)) + (bflo(u2.x) + bflo(u3.x));
        acc[1] += (bfhi(u0.x) + bfhi(u1.x)) + (bfhi(u2.x) + bfhi(u3.x));
        acc[2] += (bflo(u0.y) + bflo(u1.y)) + (bflo(u2.y) + bflo(u3.y));
        acc[3] += (bfhi(u0.y) + bfhi(u1.y)) + (bfhi(u2.y) + bfhi(u3.y));
        acc[4] += (bflo(u0.z) + bflo(u1.z)) + (bflo(u2.z) + bflo(u3.z));
        acc[5] += (bfhi(u0.z) + bfhi(u1.z)) + (bfhi(u2.z) + bfhi(u3.z));
        acc[6] += (bflo(u0.w) + bflo(u1.w)) + (bflo(u2.w) + bflo(u3.w));
        acc[7] += (bfhi(u0.w) + bfhi(u1.w)) + (bfhi(u2.w) + bfhi(u3.w));
    }
    for (; p < end; ++p) {
        uint4 u = xb4[(size_t)adj[p] * 16 + i];
        acc[0] += bflo(u.x);
        acc[1] += bfhi(u.x);
        acc[2] += bflo(u.y);
        acc[3] += bfhi(u.y);
        acc[4] += bflo(u.z);
        acc[5] += bfhi(u.z);
        acc[6] += bflo(u.w);
        acc[7] += bfhi(u.w);
    }

    float inv = 1.0f / (float)(end > beg ? (end - beg) : 1);
    uint4 r;
    r.x = packbf(acc[0] * inv, acc[1] * inv);
    r.y = packbf(acc[2] * inv, acc[3] * inv);
    r.z = packbf(acc[4] * inv, acc[5] * inv);
    r.w = packbf(acc[6] * inv, acc[7] * inv);
    aggb4[(size_t)node * 16 + i] = r;
}

// ---------------- pull_mean 64-wide (z): same structure, uint2 chunks, fp32 out ----------------

__global__ __launch_bounds__(256) void pull64_kernel(
    const uint2* __restrict__ zb2, const int* __restrict__ row_ptr,
    const int* __restrict__ adj, float* __restrict__ aggout) {
    const int l = threadIdx.x & 63;
    const int g = l >> 4;
    const int i = l & 15;
    const int node = blockIdx.x * 16 + (threadIdx.x >> 6) * 4 + g;
    const int beg = row_ptr[node], end = row_ptr[node + 1];

    float acc[4];
#pragma unroll
    for (int j = 0; j < 4; ++j) acc[j] = 0.f;

    int p = beg;
    for (; p + 4 <= end; p += 4) {
        int s0 = adj[p + 0], s1 = adj[p + 1], s2 = adj[p + 2], s3 = adj[p + 3];
        uint2 u0 = zb2[(size_t)s0 * 16 + i];
        uint2 u1 = zb2[(size_t)s1 * 16 + i];
        uint2 u2 = zb2[(size_t)s2 * 16 + i];
        uint2 u3 = zb2[(size_t)s3 * 16 + i];
        acc[0] += (bflo(u0.x) + bflo(u1.x)) + (bflo(u2.x) + bflo(u3.x));
        acc[1] += (bfhi(u0.x) + bfhi(u1.x)) + (bfhi(u2.x) + bfhi(u3.x));
        acc[2] += (bflo(u0.y) + bflo(u1.y)) + (bflo(u2.y) + bflo(u3.y));
        acc[3] += (bfhi(u0.y) + bfhi(u1.y)) + (bfhi(u2.y) + bfhi(u3.y));
    }
    for (; p < end; ++p) {
        uint2 u = zb2[(size_t)adj[p] * 16 + i];
        acc[0] += bflo(u.x);
        acc[1] += bfhi(u.x);
        acc[2] += bflo(u.y);
        acc[3] += bfhi(u.y);
    }

    float inv = 1.0f / (float)(end > beg ? (end - beg) : 1);
    float4 w;
    w.x = acc[0] * inv;
    w.y = acc[1] * inv;
    w.z = acc[2] * inv;
    w.w = acc[3] * inv;
    *(float4*)(aggout + (size_t)node * 64 + i * 4) = w;
}

// ---------------- MFMA SAGE layer (H=128): out = relu(agg@Wl + xin@Wr + b) ----------------
// FUSE_Z: additionally z = h @ Wz via LDS C->A transpose (bit-identical to a separate
// matmul over the bf16 h). __syncthreads() guarantees LDS write->read ordering.

template <bool FUSE_Z>
__global__ __launch_bounds__(256) void sage_mfma_kernel(
    const uint4* __restrict__ aggA, const uint4* __restrict__ xinA,
    const uint4* __restrict__ wfrag, const float* __restrict__ bias,
    unsigned short* __restrict__ outb,
    const uint4* __restrict__ wfz, unsigned short* __restrict__ zout) {
    extern __shared__ unsigned short hts[];  // FUSE_Z: 4 waves x [16][136]

    const int w = threadIdx.x >> 6;
    const int l = threadIdx.x & 63;
    const int r0 = blockIdx.x * 64 + w * 16;
    int arow = r0 + (l & 15);
    if (arow > NN - 1) arow = NN - 1;
    const int koff = l >> 4;

    f32x4 acc[8];
#pragma unroll
    for (int nt = 0; nt < 8; ++nt) {
        f32x4 z = {0.f, 0.f, 0.f, 0.f};
        acc[nt] = z;
    }

#pragma unroll
    for (int kt = 0; kt < 8; ++kt) {
        const uint4* Ab = (kt < 4) ? aggA : xinA;
        const int ktl = kt & 3;
        bf16x8 av = as_bf8(Ab[(size_t)arow * 16 + ktl * 4 + koff]);
#pragma unroll
        for (int nt = 0; nt < 8; ++nt) {
            bf16x8 bv = as_bf8(wfrag[(kt * 8 + nt) * 64 + l]);
            acc[nt] = __builtin_amdgcn_mfma_f32_16x16x32_bf16(av, bv, acc[nt], 0, 0, 0);
        }
    }

    const int crow0 = r0 + ((l >> 4) << 2);
    const int ccol = l & 15;
#pragma unroll
    for (int nt = 0; nt < 8; ++nt) {
        float bb = bias[nt * 16 + ccol];
#pragma unroll
        for (int q = 0; q < 4; ++q) {
            int r = crow0 + q;
            unsigned short hb = f2bf(fmaxf(acc[nt][q] + bb, 0.f));
            if (r < NN) outb[(size_t)r * 128 + nt * 16 + ccol] = hb;
            if (FUSE_Z) {
                hts[((size_t)w * 16 + ((l >> 4) << 2) + q) * 136 + nt * 16 + ccol] = hb;
            }
        }
    }

    if (FUSE_Z) {
        __syncthreads();
        f32x4 accz[4];
#pragma unroll
        for (int nt = 0; nt < 4; ++nt) {
            f32x4 z = {0.f, 0.f, 0.f, 0.f};
            accz[nt] = z;
        }
#pragma unroll
        for (int kt = 0; kt < 4; ++kt) {
            const uint4 hv =
                *(const uint4*)&hts[((size_t)w * 16 + (l & 15)) * 136 + kt * 32 + (l >> 4) * 8];
            bf16x8 av = as_bf8(hv);
#pragma unroll
            for (int nt = 0; nt < 4; ++nt) {
                bf16x8 bv = as_bf8(wfz[(kt * 4 + nt) * 64 + l]);
                accz[nt] = __builtin_amdgcn_mfma_f32_16x16x32_bf16(av, bv, accz[nt], 0, 0, 0);
            }
        }
#pragma unroll
        for (int nt = 0; nt < 4; ++nt) {
#pragma unroll
            for (int q = 0; q < 4; ++q) {
                int r = crow0 + q;
                if (r < NN) zout[(size_t)r * 64 + nt * 16 + ccol] = f2bf(accz[nt][q]);
            }
        }
    }
}

// ---------------- final MFMA matmul: out = h2 @ W3r + agg3 + b3 (fp32) ----------------

__global__ __launch_bounds__(256) void mm64_final_kernel(
    const uint4* __restrict__ A, const uint4* __restrict__ wfrag,
    const float* __restrict__ addin, const float* __restrict__ bias,
    float* __restrict__ out) {
    const int w = threadIdx.x >> 6;
    const int l = threadIdx.x & 63;
    const int r0 = blockIdx.x * 64 + w * 16;
    int arow = r0 + (l & 15);
    if (arow > NN - 1) arow = NN - 1;
    const int koff = l >> 4;

    f32x4 acc[4];
#pragma unroll
    for (int nt = 0; nt < 4; ++nt) {
        f32x4 z = {0.f, 0.f, 0.f, 0.f};
        acc[nt] = z;
    }

#pragma unroll
    for (int kt = 0; kt < 4; ++kt) {
        bf16x8 av = as_bf8(A[(size_t)arow * 16 + kt * 4 + koff]);
#pragma unroll
        for (int nt = 0; nt < 4; ++nt) {
            bf16x8 bv = as_bf8(wfrag[(kt * 4 + nt) * 64 + l]);
            acc[nt] = __builtin_amdgcn_mfma_f32_16x16x32_bf16(av, bv, acc[nt], 0, 0, 0);
        }
    }

    const int crow0 = r0 + ((l >> 4) << 2);
    const int ccol = l & 15;
#pragma unroll
    for (int nt = 0; nt < 4; ++nt) {
        int col = nt * 16 + ccol;
#pragma unroll
        for (int q = 0; q < 4; ++q) {
            int r = crow0 + q;
            if (r < NN) {
                out[(size_t)r * 64 + col] =
                    acc[nt][q] + addin[(size_t)r * 64 + col] + bias[col];
            }
        }
    }
}

// ---------------- launcher ----------------

extern "C" void kernel_launch(void* const* d_in, const int* in_sizes, int n_in,
                              void* d_out, int out_size, void* d_ws, size_t ws_size,
                              hipStream_t stream) {
    (void)in_sizes; (void)n_in; (void)out_size; (void)ws_size;

    const float* x   = (const float*)d_in[0];
    const int* eidx  = (const int*)d_in[1];
    const int* src   = eidx;
    const int* dst   = eidx + NE;
    const float* W1l = (const float*)d_in[2];
    const float* W1r = (const float*)d_in[3];
    const float* b1  = (const float*)d_in[4];
    const float* W2l = (const float*)d_in[5];
    const float* W2r = (const float*)d_in[6];
    const float* b2  = (const float*)d_in[7];
    const float* W3l = (const float*)d_in[8];
    const float* W3r = (const float*)d_in[9];
    const float* b3  = (const float*)d_in[10];
    float* out = (float*)d_out;

    size_t off = 0;
    auto carve = [&](size_t bytes) -> void* {
        void* p = (char*)d_ws + off;
        off += (bytes + 255) & ~(size_t)255;
        return p;
    };
    int* gcur    = (int*)carve((size_t)NB * 4);
    int* row_ptr = (int*)carve((size_t)(NN + 1) * 4);
    int* adj     = (int*)carve((size_t)NE * 4);
    unsigned* buckets = (unsigned*)carve((size_t)NB * CAP * 4);         // 7.6 MB
    unsigned int* x_bf  = (unsigned int*)carve((size_t)NN * 64 * 4);    // [NN][128] bf16
    unsigned int* agg   = (unsigned int*)carve((size_t)NN * 64 * 4);    // [NN][128] bf16
    unsigned int* h1_bf = (unsigned int*)carve((size_t)NN * 64 * 4);
    unsigned int* h2_bf = (unsigned int*)carve((size_t)NN * 64 * 4);
    unsigned int* z_bf  = (unsigned int*)carve((size_t)NN * 32 * 4);    // [NN][64] bf16
    float* agg3         = (float*)carve((size_t)NN * 64 * 4);           // [NN][64] fp32
    uint4* wf1  = (uint4*)carve((size_t)8 * 8 * 64 * 16);
    uint4* wf2  = (uint4*)carve((size_t)8 * 8 * 64 * 16);
    uint4* wf3l = (uint4*)carve((size_t)4 * 4 * 64 * 16);
    uint4* wf3r = (uint4*)carve((size_t)4 * 4 * 64 * 16);

    const int pgrid = NN / 16;                              // 6250 exact
    const int mgrid = (NN + 63) / 64;                       // 1563

    // --- fused CSR-scatter + prep (independent halves), then finalize (inline scan) ---
    (void)hipMemsetAsync(gcur, 0, (size_t)NB * 4, stream);
    scatter_prep_kernel<<<NBLK_A + PREP_BLKS, 256, 0, stream>>>(
        src, dst, gcur, buckets, x, x_bf, W1l, W1r, W2l, W2r, W3l, W3r,
        wf1, wf2, wf3l, wf3r);
    csr_finalize_kernel<<<NB, 256, 0, stream>>>(buckets, gcur, row_ptr, adj);

    // --- layer 1 ---
    pull128_kernel<<<pgrid, 256, 0, stream>>>((const uint4*)x_bf, row_ptr, adj, (uint4*)agg);
    sage_mfma_kernel<false><<<mgrid, 256, 0, stream>>>(
        (const uint4*)agg, (const uint4*)x_bf, wf1, b1, (unsigned short*)h1_bf,
        nullptr, nullptr);
    // --- layer 2 (+ fused z = h2 @ W3l) ---
    pull128_kernel<<<pgrid, 256, 0, stream>>>((const uint4*)h1_bf, row_ptr, adj, (uint4*)agg);
    sage_mfma_kernel<true><<<mgrid, 256, 4 * 16 * 136 * 2, stream>>>(
        (const uint4*)agg, (const uint4*)h1_bf, wf2, b2, (unsigned short*)h2_bf,
        wf3l, (unsigned short*)z_bf);
    // --- layer 3 ---
    pull64_kernel<<<pgrid, 256, 0, stream>>>((const uint2*)z_bf, row_ptr, adj, agg3);
    mm64_final_kernel<<<mgrid, 256, 0, stream>>>((const uint4*)h2_bf, wf3r, agg3, b3, out);
}